// Round 1
// baseline (902.506 us; speedup 1.0000x reference)
//
#include <hip/hip_runtime.h>
#include <hip/hip_bf16.h>

#define B_  8
#define D_  256
#define N_  8192
#define M_  8192
#define O1_ 512     // 2D
#define K1_ 768     // 3D
#define K2_ 512     // 2D

typedef unsigned short u16;
typedef __attribute__((ext_vector_type(8))) short bf8;   // 8 bf16 = 4 VGPRs
typedef __attribute__((ext_vector_type(4))) float f4;

static __device__ __forceinline__ float bf2f(u16 u) {
    unsigned v = ((unsigned)u) << 16;
    return __uint_as_float(v);
}
static __device__ __forceinline__ u16 f2bf(float f) {
    __hip_bfloat16 h = __float2bfloat16(f);
    return *reinterpret_cast<u16*>(&h);
}
// async global->LDS, 16B per lane; LDS dest = wave-uniform base + lane*16
static __device__ __forceinline__ void gl_lds16(const u16* g, u16* l) {
    __builtin_amdgcn_global_load_lds((const __attribute__((address_space(1))) void*)g,
                                     (__attribute__((address_space(3))) void*)l, 16, 0, 0);
}

// ---------------- transpose f32 [B][R][C] -> bf16 [B][C][R] ----------------
__global__ __launch_bounds__(256) void k_transpose_bf16(const float* __restrict__ src,
                                                        u16* __restrict__ dst, int R, int C) {
    __shared__ float t[32][33];
    const int b  = blockIdx.z;
    const int c0 = blockIdx.x * 32, r0 = blockIdx.y * 32;
    const int tx = threadIdx.x, ty = threadIdx.y;     // block (32,8)
    const float* s = src + (size_t)b * R * C;
    u16* d = dst + (size_t)b * C * R;
#pragma unroll
    for (int i = 0; i < 4; ++i) {
        int r = r0 + ty + i * 8;
        t[ty + i * 8][tx] = s[(size_t)r * C + (c0 + tx)];
    }
    __syncthreads();
#pragma unroll
    for (int i = 0; i < 4; ++i) {
        int c = c0 + ty + i * 8;
        d[(size_t)c * R + (r0 + tx)] = f2bf(t[tx][ty + i * 8]);
    }
}

// ---------------- weights f32 -> bf16 ----------------
__global__ __launch_bounds__(256) void k_convert_w(const float* __restrict__ W1, const float* __restrict__ W2,
                                                   u16* __restrict__ W1b, u16* __restrict__ W2b) {
    int i = blockIdx.x * 256 + threadIdx.x;
    const int n1 = O1_ * K1_;
    const int n2 = D_ * K2_;
    if (i < n1) W1b[i] = f2bf(W1[i]);
    int j = i - n1;
    if (j >= 0 && j < n2) W2b[j] = f2bf(W2[j]);
}

// ---------------- GEMM1: h[b][m][o] = W1 @ msg + b1 ----------------
// msg k-segments: [0,256) Tld[idx[m]], [256,512) Tld[idx[m^1]], [512,768) Tle[m]
__global__ __launch_bounds__(256) void k_gemm1(const u16* __restrict__ W1b,
                                               const u16* __restrict__ Tld,
                                               const u16* __restrict__ Tle,
                                               const int* __restrict__ idx,
                                               const float* __restrict__ b1,
                                               u16* __restrict__ hbuf) {
    __shared__ u16 At[128 * 32];
    __shared__ u16 Bt[128 * 32];
    const int b  = blockIdx.z;
    const int o0 = blockIdx.y * 128;
    const int m0 = blockIdx.x * 128;
    const int tid = threadIdx.x;
    const int w = tid >> 6, l = tid & 63;
    const int lr = l >> 2;          // staging row-in-group 0..15
    const int lc = (l & 3) * 8;     // ushort offset (16B) within 64B row

    const u16* pA[2]; const u16* pB0[2]; const u16* pB1[2]; const u16* pB2[2];
#pragma unroll
    for (int t = 0; t < 2; ++t) {
        int row = t * 64 + w * 16 + lr;                  // 0..127
        pA[t] = W1b + (size_t)(o0 + row) * K1_ + lc;
        int m  = m0 + row;
        int na = idx[b * M_ + m];
        int nb = idx[b * M_ + (m ^ 1)];
        pB0[t] = Tld + (size_t)(b * N_ + na) * D_ + lc;
        pB1[t] = Tld + (size_t)(b * N_ + nb) * D_ + lc;
        pB2[t] = Tle + (size_t)(b * M_ + m) * D_ + lc;
    }

    const int wr = w >> 1, wc = w & 1;
    f4 acc[4][4];
#pragma unroll
    for (int i = 0; i < 4; ++i)
#pragma unroll
        for (int j = 0; j < 4; ++j) acc[i][j] = {0.f, 0.f, 0.f, 0.f};

    const int aoff = (wr * 64 + (l & 15)) * 32 + (l >> 4) * 8;
    const int boff = (wc * 64 + (l & 15)) * 32 + (l >> 4) * 8;

    for (int kk = 0; kk < 24; ++kk) {
        const int seg  = kk >> 3;
        const int coff = (kk & 7) * 32;   // ushorts within source row
#pragma unroll
        for (int t = 0; t < 2; ++t) {
            gl_lds16(pA[t] + kk * 32, At + (t * 64 + w * 16) * 32);
            const u16* src = (seg == 0) ? (pB0[t] + coff)
                           : (seg == 1) ? (pB1[t] + coff)
                                        : (pB2[t] + coff);
            gl_lds16(src, Bt + (t * 64 + w * 16) * 32);
        }
        __syncthreads();
        bf8 aF[4], bF[4];
#pragma unroll
        for (int i = 0; i < 4; ++i) aF[i] = *reinterpret_cast<const bf8*>(&At[aoff + i * 16 * 32]);
#pragma unroll
        for (int j = 0; j < 4; ++j) bF[j] = *reinterpret_cast<const bf8*>(&Bt[boff + j * 16 * 32]);
#pragma unroll
        for (int i = 0; i < 4; ++i)
#pragma unroll
            for (int j = 0; j < 4; ++j)
                acc[i][j] = __builtin_amdgcn_mfma_f32_16x16x32_bf16(aF[i], bF[j], acc[i][j], 0, 0, 0);
        __syncthreads();
    }

    // epilogue: +b1, store bf16 to hbuf[b][m][o] (o fast)
#pragma unroll
    for (int j = 0; j < 4; ++j) {
        int m = m0 + wc * 64 + j * 16 + (l & 15);
        size_t rowbase = (size_t)(b * M_ + m) * O1_;
#pragma unroll
        for (int i = 0; i < 4; ++i) {
            int orow = o0 + wr * 64 + i * 16 + (l >> 4) * 4;
            ushort4 pk;
            pk.x = f2bf(acc[i][j].x + b1[orow + 0]);
            pk.y = f2bf(acc[i][j].y + b1[orow + 1]);
            pk.z = f2bf(acc[i][j].z + b1[orow + 2]);
            pk.w = f2bf(acc[i][j].w + b1[orow + 3]);
            *reinterpret_cast<ushort4*>(&hbuf[rowbase + orow]) = pk;
        }
    }
}

// ---------------- per-channel sum / sumsq over h ----------------
__global__ __launch_bounds__(256) void k_stats(const u16* __restrict__ hbuf, float* __restrict__ stats) {
    const int t = threadIdx.x;
    const size_t row0 = (size_t)blockIdx.x * 256;
    float s0 = 0.f, q0 = 0.f, s1 = 0.f, q1 = 0.f;
    for (int r = 0; r < 256; ++r) {
        const u16* p = hbuf + (row0 + r) * O1_;
        float v0 = bf2f(p[t]);
        float v1 = bf2f(p[t + 256]);
        s0 += v0; q0 += v0 * v0;
        s1 += v1; q1 += v1 * v1;
    }
    atomicAdd(&stats[t], s0);
    atomicAdd(&stats[O1_ + t], q0);
    atomicAdd(&stats[t + 256], s1);
    atomicAdd(&stats[O1_ + t + 256], q1);
}

__global__ void k_finalize_ac(const float* __restrict__ stats, const float* __restrict__ g1,
                              const float* __restrict__ bt1, float* __restrict__ ac) {
    int o = blockIdx.x * 256 + threadIdx.x;
    if (o >= O1_) return;
    const float inv = 1.0f / ((float)B_ * (float)M_);
    float mean = stats[o] * inv;
    float var  = stats[O1_ + o] * inv - mean * mean;
    var = fmaxf(var, 0.0f);
    float a = g1[o] * rsqrtf(var + 1e-5f);
    ac[o] = a;
    ac[O1_ + o] = bt1[o] - mean * a;
}

// ---------------- BN + ReLU in place on h ----------------
__global__ __launch_bounds__(256) void k_bnrelu(u16* __restrict__ hbuf, const float* __restrict__ ac) {
    const size_t nv = (size_t)B_ * M_ * (O1_ / 8);
    const size_t stride = (size_t)gridDim.x * blockDim.x;
    for (size_t i = (size_t)blockIdx.x * blockDim.x + threadIdx.x; i < nv; i += stride) {
        size_t e = i * 8;
        int o = (int)(e & (O1_ - 1));
        ushort4* p = reinterpret_cast<ushort4*>(&hbuf[e]);
        ushort4 v0 = p[0], v1 = p[1];
        ushort4 r0, r1;
        r0.x = f2bf(fmaxf(bf2f(v0.x) * ac[o + 0] + ac[O1_ + o + 0], 0.0f));
        r0.y = f2bf(fmaxf(bf2f(v0.y) * ac[o + 1] + ac[O1_ + o + 1], 0.0f));
        r0.z = f2bf(fmaxf(bf2f(v0.z) * ac[o + 2] + ac[O1_ + o + 2], 0.0f));
        r0.w = f2bf(fmaxf(bf2f(v0.w) * ac[o + 3] + ac[O1_ + o + 3], 0.0f));
        r1.x = f2bf(fmaxf(bf2f(v1.x) * ac[o + 4] + ac[O1_ + o + 4], 0.0f));
        r1.y = f2bf(fmaxf(bf2f(v1.y) * ac[o + 5] + ac[O1_ + o + 5], 0.0f));
        r1.z = f2bf(fmaxf(bf2f(v1.z) * ac[o + 6] + ac[O1_ + o + 6], 0.0f));
        r1.w = f2bf(fmaxf(bf2f(v1.w) * ac[o + 7] + ac[O1_ + o + 7], 0.0f));
        p[0] = r0; p[1] = r1;
    }
}

// ---------------- counts histogram ----------------
__global__ void k_count(const int* __restrict__ idx, float* __restrict__ cnt) {
    int i = blockIdx.x * 256 + threadIdx.x;
    if (i < B_ * M_) {
        int b = i >> 13;   // / M_
        atomicAdd(&cnt[b * N_ + idx[i]], 1.0f);
    }
}

// ---------------- GEMM2: up = W2 @ relu(bn(h)) + b2, scatter-add to sums[b][n][d] ----------------
__global__ __launch_bounds__(256) void k_gemm2(const u16* __restrict__ W2b,
                                               const u16* __restrict__ hbuf,
                                               const int* __restrict__ idx,
                                               const float* __restrict__ b2,
                                               float* __restrict__ sums) {
    __shared__ u16 At[128 * 32];
    __shared__ u16 Bt[128 * 32];
    const int b  = blockIdx.z;
    const int d0 = blockIdx.y * 128;
    const int m0 = blockIdx.x * 128;
    const int tid = threadIdx.x;
    const int w = tid >> 6, l = tid & 63;
    const int lr = l >> 2, lc = (l & 3) * 8;

    const u16* pA[2]; const u16* pB[2];
#pragma unroll
    for (int t = 0; t < 2; ++t) {
        int row = t * 64 + w * 16 + lr;
        pA[t] = W2b + (size_t)(d0 + row) * K2_ + lc;
        int m  = m0 + row;
        pB[t] = hbuf + (size_t)(b * M_ + m) * O1_ + lc;
    }
    const int wr = w >> 1, wc = w & 1;
    f4 acc[4][4];
#pragma unroll
    for (int i = 0; i < 4; ++i)
#pragma unroll
        for (int j = 0; j < 4; ++j) acc[i][j] = {0.f, 0.f, 0.f, 0.f};

    const int aoff = (wr * 64 + (l & 15)) * 32 + (l >> 4) * 8;
    const int boff = (wc * 64 + (l & 15)) * 32 + (l >> 4) * 8;

    for (int kk = 0; kk < 16; ++kk) {
#pragma unroll
        for (int t = 0; t < 2; ++t) {
            gl_lds16(pA[t] + kk * 32, At + (t * 64 + w * 16) * 32);
            gl_lds16(pB[t] + kk * 32, Bt + (t * 64 + w * 16) * 32);
        }
        __syncthreads();
        bf8 aF[4], bF[4];
#pragma unroll
        for (int i = 0; i < 4; ++i) aF[i] = *reinterpret_cast<const bf8*>(&At[aoff + i * 16 * 32]);
#pragma unroll
        for (int j = 0; j < 4; ++j) bF[j] = *reinterpret_cast<const bf8*>(&Bt[boff + j * 16 * 32]);
#pragma unroll
        for (int i = 0; i < 4; ++i)
#pragma unroll
            for (int j = 0; j < 4; ++j)
                acc[i][j] = __builtin_amdgcn_mfma_f32_16x16x32_bf16(aF[i], bF[j], acc[i][j], 0, 0, 0);
        __syncthreads();
    }

    // epilogue: scatter-add into sums[b][n][d]
#pragma unroll
    for (int j = 0; j < 4; ++j) {
        int m = m0 + wc * 64 + j * 16 + (l & 15);
        int n = idx[b * M_ + m];
        float* dstp = sums + (size_t)(b * N_ + n) * D_;
#pragma unroll
        for (int i = 0; i < 4; ++i) {
            int d = d0 + wr * 64 + i * 16 + (l >> 4) * 4;
            atomicAdd(&dstp[d + 0], acc[i][j].x + b2[d + 0]);
            atomicAdd(&dstp[d + 1], acc[i][j].y + b2[d + 1]);
            atomicAdd(&dstp[d + 2], acc[i][j].z + b2[d + 2]);
            atomicAdd(&dstp[d + 3], acc[i][j].w + b2[d + 3]);
        }
    }
}

// ---------------- out[b][d][n] = ldesc + sums[b][n][d] / max(cnt,1) ----------------
__global__ __launch_bounds__(256) void k_finalize(const float* __restrict__ ldesc,
                                                  const float* __restrict__ sums,
                                                  const float* __restrict__ cnt,
                                                  float* __restrict__ out) {
    __shared__ float t[32][33];
    __shared__ float ci[32];
    const int b  = blockIdx.z;
    const int n0 = blockIdx.x * 32, d0 = blockIdx.y * 32;
    const int tx = threadIdx.x, ty = threadIdx.y;   // (32,8)
#pragma unroll
    for (int i = 0; i < 4; ++i) {
        int n = n0 + ty + i * 8;
        t[ty + i * 8][tx] = sums[(size_t)(b * N_ + n) * D_ + (d0 + tx)];
    }
    if (ty == 0) {
        float c = cnt[b * N_ + n0 + tx];
        ci[tx] = 1.0f / fmaxf(c, 1.0f);
    }
    __syncthreads();
#pragma unroll
    for (int i = 0; i < 4; ++i) {
        int d = d0 + ty + i * 8;
        size_t off = (size_t)(b * D_ + d) * N_ + (n0 + tx);
        out[off] = ldesc[off] + t[tx][ty + i * 8] * ci[tx];
    }
}

__global__ void k_marker(float* out, float v) { out[0] = v; }

extern "C" void kernel_launch(void* const* d_in, const int* in_sizes, int n_in,
                              void* d_out, int out_size, void* d_ws, size_t ws_size,
                              hipStream_t stream) {
    const float* ldesc0 = (const float*)d_in[0];
    const float* ldesc1 = (const float*)d_in[1];
    const float* le0    = (const float*)d_in[2];
    const float* le1    = (const float*)d_in[3];
    const int*   idx0   = (const int*)d_in[4];
    const int*   idx1   = (const int*)d_in[5];
    const float* W1     = (const float*)d_in[6];
    const float* b1     = (const float*)d_in[7];
    const float* g1     = (const float*)d_in[8];
    const float* bt1    = (const float*)d_in[9];
    const float* W2     = (const float*)d_in[10];
    const float* b2     = (const float*)d_in[11];
    float* out = (float*)d_out;

    char* ws = (char*)d_ws;
    const size_t oTld   = 0;                            // bf16 [B][N][D]   33,554,432 B
    const size_t oTle   = 33554432;                     // bf16 [B][M][D]   33,554,432 B
    const size_t oSums  = 0;                            // f32 [B][N][D] (aliases Tld+Tle region)
    const size_t oH     = 67108864;                     // bf16 [B][M][O1]  67,108,864 B
    const size_t oW1b   = 134217728;                    // 786,432 B
    const size_t oW2b   = oW1b + 786432;                // 262,144 B
    const size_t oStats = oW2b + 262144;                // 4,096 B
    const size_t oAC    = oStats + 4096;                // 4,096 B
    const size_t oCnt   = oAC + 4096;                   // 262,144 B
    const size_t NEED   = oCnt + (size_t)B_ * N_ * 4;
    if (ws_size < NEED) {
        // debug channel: absmax will read ~1000 + ws_MB
        k_marker<<<1, 1, 0, stream>>>(out, 1000.0f + (float)(ws_size >> 20));
        return;
    }
    u16*   Tld   = (u16*)(ws + oTld);
    u16*   Tle   = (u16*)(ws + oTle);
    float* sums  = (float*)(ws + oSums);
    u16*   hbuf  = (u16*)(ws + oH);
    u16*   W1b   = (u16*)(ws + oW1b);
    u16*   W2b   = (u16*)(ws + oW2b);
    float* stats = (float*)(ws + oStats);
    float* ac    = (float*)(ws + oAC);
    float* cnt   = (float*)(ws + oCnt);

    k_convert_w<<<2048, 256, 0, stream>>>(W1, W2, W1b, W2b);

    const dim3 tb(32, 8);
    for (int s = 0; s < 2; ++s) {
        const float* ld  = s ? ldesc1 : ldesc0;
        const float* le  = s ? le1 : le0;
        const int*   idx = s ? idx1 : idx0;
        float* outp = out + (size_t)s * B_ * D_ * N_;

        k_transpose_bf16<<<dim3(N_ / 32, D_ / 32, B_), tb, 0, stream>>>(ld, Tld, D_, N_);
        k_transpose_bf16<<<dim3(M_ / 32, D_ / 32, B_), tb, 0, stream>>>(le, Tle, D_, M_);
        k_gemm1<<<dim3(M_ / 128, O1_ / 128, B_), 256, 0, stream>>>(W1b, Tld, Tle, idx, b1, hbuf);
        hipMemsetAsync(stats, 0, 4096, stream);
        k_stats<<<256, 256, 0, stream>>>(hbuf, stats);
        k_finalize_ac<<<2, 256, 0, stream>>>(stats, g1, bt1, ac);
        k_bnrelu<<<2048, 256, 0, stream>>>(hbuf, ac);
        hipMemsetAsync(sums, 0, (size_t)B_ * N_ * D_ * 4, stream);
        hipMemsetAsync(cnt, 0, (size_t)B_ * N_ * 4, stream);
        k_count<<<B_ * M_ / 256, 256, 0, stream>>>(idx, cnt);
        k_gemm2<<<dim3(M_ / 128, D_ / 128, B_), 256, 0, stream>>>(W2b, hbuf, idx, b2, sums);
        k_finalize<<<dim3(N_ / 32, D_ / 32, B_), tb, 0, stream>>>(ld, sums, cnt, outp);
    }
}

// Round 3
// 505.489 us; speedup vs baseline: 1.7854x; 1.7854x over previous
//
#include <hip/hip_runtime.h>
#include <hip/hip_bf16.h>

#define B_  8
#define D_  256
#define N_  8192
#define M_  8192
#define O1_ 512     // 2D
#define K1_ 768     // 3D
#define K2_ 512     // 2D

typedef unsigned short u16;
typedef __attribute__((ext_vector_type(8))) short bf8;   // 8 bf16 = 4 VGPRs
typedef __attribute__((ext_vector_type(4))) float f4;

static __device__ __forceinline__ float bf2f(u16 u) {
    unsigned v = ((unsigned)u) << 16;
    return __uint_as_float(v);
}
static __device__ __forceinline__ u16 f2bf(float f) {
    __hip_bfloat16 h = __float2bfloat16(f);
    return *reinterpret_cast<u16*>(&h);
}
// async global->LDS, 16B per lane; LDS dest = wave-uniform base + lane*16
static __device__ __forceinline__ void gl_lds16(const u16* g, u16* l) {
    __builtin_amdgcn_global_load_lds((const __attribute__((address_space(1))) void*)g,
                                     (__attribute__((address_space(3))) void*)l, 16, 0, 0);
}

// ---------------- transpose f32 [B][R][C] -> bf16 [B][C][R] ----------------
__global__ __launch_bounds__(256) void k_transpose_bf16(const float* __restrict__ src,
                                                        u16* __restrict__ dst, int R, int C) {
    __shared__ float t[32][33];
    const int b  = blockIdx.z;
    const int c0 = blockIdx.x * 32, r0 = blockIdx.y * 32;
    const int tx = threadIdx.x, ty = threadIdx.y;     // block (32,8)
    const float* s = src + (size_t)b * R * C;
    u16* d = dst + (size_t)b * C * R;
#pragma unroll
    for (int i = 0; i < 4; ++i) {
        int r = r0 + ty + i * 8;
        t[ty + i * 8][tx] = s[(size_t)r * C + (c0 + tx)];
    }
    __syncthreads();
#pragma unroll
    for (int i = 0; i < 4; ++i) {
        int c = c0 + ty + i * 8;
        d[(size_t)c * R + (r0 + tx)] = f2bf(t[tx][ty + i * 8]);
    }
}

// ---------------- weights f32 -> bf16 ----------------
__global__ __launch_bounds__(256) void k_convert_w(const float* __restrict__ W1, const float* __restrict__ W2,
                                                   u16* __restrict__ W1b, u16* __restrict__ W2b) {
    int i = blockIdx.x * 256 + threadIdx.x;
    const int n1 = O1_ * K1_;
    const int n2 = D_ * K2_;
    if (i < n1) W1b[i] = f2bf(W1[i]);
    int j = i - n1;
    if (j >= 0 && j < n2) W2b[j] = f2bf(W2[j]);
}

// ---------------- GEMM1: h[b][m][o] = W1 @ msg + b1 ----------------
// msg k-segments: [0,256) Tld[idx[m]], [256,512) Tld[idx[m^1]], [512,768) Tle[m]
__global__ __launch_bounds__(256) void k_gemm1(const u16* __restrict__ W1b,
                                               const u16* __restrict__ Tld,
                                               const u16* __restrict__ Tle,
                                               const int* __restrict__ idx,
                                               const float* __restrict__ b1,
                                               u16* __restrict__ hbuf) {
    __shared__ u16 At[128 * 32];
    __shared__ u16 Bt[128 * 32];
    const int b  = blockIdx.z;
    const int o0 = blockIdx.y * 128;
    const int m0 = blockIdx.x * 128;
    const int tid = threadIdx.x;
    const int w = tid >> 6, l = tid & 63;
    const int lr = l >> 2;          // staging row-in-group 0..15
    const int lc = (l & 3) * 8;     // ushort offset (16B) within 64B row

    const u16* pA[2]; const u16* pB0[2]; const u16* pB1[2]; const u16* pB2[2];
#pragma unroll
    for (int t = 0; t < 2; ++t) {
        int row = t * 64 + w * 16 + lr;                  // 0..127
        pA[t] = W1b + (size_t)(o0 + row) * K1_ + lc;
        int m  = m0 + row;
        int na = idx[b * M_ + m];
        int nb = idx[b * M_ + (m ^ 1)];
        pB0[t] = Tld + (size_t)(b * N_ + na) * D_ + lc;
        pB1[t] = Tld + (size_t)(b * N_ + nb) * D_ + lc;
        pB2[t] = Tle + (size_t)(b * M_ + m) * D_ + lc;
    }

    const int wr = w >> 1, wc = w & 1;
    f4 acc[4][4];
#pragma unroll
    for (int i = 0; i < 4; ++i)
#pragma unroll
        for (int j = 0; j < 4; ++j) acc[i][j] = {0.f, 0.f, 0.f, 0.f};

    const int aoff = (wr * 64 + (l & 15)) * 32 + (l >> 4) * 8;
    const int boff = (wc * 64 + (l & 15)) * 32 + (l >> 4) * 8;

    for (int kk = 0; kk < 24; ++kk) {
        const int seg  = kk >> 3;
        const int coff = (kk & 7) * 32;   // ushorts within source row
#pragma unroll
        for (int t = 0; t < 2; ++t) {
            gl_lds16(pA[t] + kk * 32, At + (t * 64 + w * 16) * 32);
            const u16* src = (seg == 0) ? (pB0[t] + coff)
                           : (seg == 1) ? (pB1[t] + coff)
                                        : (pB2[t] + coff);
            gl_lds16(src, Bt + (t * 64 + w * 16) * 32);
        }
        __syncthreads();
        bf8 aF[4], bF[4];
#pragma unroll
        for (int i = 0; i < 4; ++i) aF[i] = *reinterpret_cast<const bf8*>(&At[aoff + i * 16 * 32]);
#pragma unroll
        for (int j = 0; j < 4; ++j) bF[j] = *reinterpret_cast<const bf8*>(&Bt[boff + j * 16 * 32]);
#pragma unroll
        for (int i = 0; i < 4; ++i)
#pragma unroll
            for (int j = 0; j < 4; ++j)
                acc[i][j] = __builtin_amdgcn_mfma_f32_16x16x32_bf16(aF[i], bF[j], acc[i][j], 0, 0, 0);
        __syncthreads();
    }

    // epilogue: +b1, store bf16 to hbuf[b][m][o] (o fast)
#pragma unroll
    for (int j = 0; j < 4; ++j) {
        int m = m0 + wc * 64 + j * 16 + (l & 15);
        size_t rowbase = (size_t)(b * M_ + m) * O1_;
#pragma unroll
        for (int i = 0; i < 4; ++i) {
            int orow = o0 + wr * 64 + i * 16 + (l >> 4) * 4;
            ushort4 pk;
            pk.x = f2bf(acc[i][j].x + b1[orow + 0]);
            pk.y = f2bf(acc[i][j].y + b1[orow + 1]);
            pk.z = f2bf(acc[i][j].z + b1[orow + 2]);
            pk.w = f2bf(acc[i][j].w + b1[orow + 3]);
            *reinterpret_cast<ushort4*>(&hbuf[rowbase + orow]) = pk;
        }
    }
}

// ---------------- per-channel sum / sumsq over h ----------------
__global__ __launch_bounds__(256) void k_stats(const u16* __restrict__ hbuf, float* __restrict__ stats) {
    const int t = threadIdx.x;
    const size_t row0 = (size_t)blockIdx.x * 256;
    float s0 = 0.f, q0 = 0.f, s1 = 0.f, q1 = 0.f;
    for (int r = 0; r < 256; ++r) {
        const u16* p = hbuf + (row0 + r) * O1_;
        float v0 = bf2f(p[t]);
        float v1 = bf2f(p[t + 256]);
        s0 += v0; q0 += v0 * v0;
        s1 += v1; q1 += v1 * v1;
    }
    atomicAdd(&stats[t], s0);
    atomicAdd(&stats[O1_ + t], q0);
    atomicAdd(&stats[t + 256], s1);
    atomicAdd(&stats[O1_ + t + 256], q1);
}

__global__ void k_finalize_ac(const float* __restrict__ stats, const float* __restrict__ g1,
                              const float* __restrict__ bt1, float* __restrict__ ac) {
    int o = blockIdx.x * 256 + threadIdx.x;
    if (o >= O1_) return;
    const float inv = 1.0f / ((float)B_ * (float)M_);
    float mean = stats[o] * inv;
    float var  = stats[O1_ + o] * inv - mean * mean;
    var = fmaxf(var, 0.0f);
    float a = g1[o] * rsqrtf(var + 1e-5f);
    ac[o] = a;
    ac[O1_ + o] = bt1[o] - mean * a;
}

// ---------------- BN + ReLU in place on h ----------------
__global__ __launch_bounds__(256) void k_bnrelu(u16* __restrict__ hbuf, const float* __restrict__ ac) {
    const size_t nv = (size_t)B_ * M_ * (O1_ / 8);
    const size_t stride = (size_t)gridDim.x * blockDim.x;
    for (size_t i = (size_t)blockIdx.x * blockDim.x + threadIdx.x; i < nv; i += stride) {
        size_t e = i * 8;
        int o = (int)(e & (O1_ - 1));
        ushort4* p = reinterpret_cast<ushort4*>(&hbuf[e]);
        ushort4 v0 = p[0], v1 = p[1];
        ushort4 r0, r1;
        r0.x = f2bf(fmaxf(bf2f(v0.x) * ac[o + 0] + ac[O1_ + o + 0], 0.0f));
        r0.y = f2bf(fmaxf(bf2f(v0.y) * ac[o + 1] + ac[O1_ + o + 1], 0.0f));
        r0.z = f2bf(fmaxf(bf2f(v0.z) * ac[o + 2] + ac[O1_ + o + 2], 0.0f));
        r0.w = f2bf(fmaxf(bf2f(v0.w) * ac[o + 3] + ac[O1_ + o + 3], 0.0f));
        r1.x = f2bf(fmaxf(bf2f(v1.x) * ac[o + 4] + ac[O1_ + o + 4], 0.0f));
        r1.y = f2bf(fmaxf(bf2f(v1.y) * ac[o + 5] + ac[O1_ + o + 5], 0.0f));
        r1.z = f2bf(fmaxf(bf2f(v1.z) * ac[o + 6] + ac[O1_ + o + 6], 0.0f));
        r1.w = f2bf(fmaxf(bf2f(v1.w) * ac[o + 7] + ac[O1_ + o + 7], 0.0f));
        p[0] = r0; p[1] = r1;
    }
}

// ---------------- CSR build: count -> scan -> fill ----------------
__global__ void k_count_int(const int* __restrict__ idx, int* __restrict__ cnt) {
    int i = blockIdx.x * 256 + threadIdx.x;
    if (i < B_ * M_) atomicAdd(&cnt[(i >> 13) * N_ + idx[i]], 1);
}

__global__ __launch_bounds__(1024) void k_scan(const int* __restrict__ cnt, int* __restrict__ offs,
                                               int* __restrict__ fill) {
    __shared__ int wsum[1024];
    const int b = blockIdx.x;
    const int t = threadIdx.x;
    const int base = b * N_;
    int v[8]; int s = 0;
#pragma unroll
    for (int k = 0; k < 8; ++k) { v[k] = cnt[base + t * 8 + k]; s += v[k]; }
    wsum[t] = s;
    __syncthreads();
    for (int off = 1; off < 1024; off <<= 1) {
        int add = (t >= off) ? wsum[t - off] : 0;
        __syncthreads();
        wsum[t] += add;
        __syncthreads();
    }
    int run = (t > 0) ? wsum[t - 1] : 0;
#pragma unroll
    for (int k = 0; k < 8; ++k) {
        offs[base + t * 8 + k] = run;
        fill[base + t * 8 + k] = run;
        run += v[k];
    }
}

__global__ void k_fill(const int* __restrict__ idx, int* __restrict__ fill, int* __restrict__ mlist) {
    int i = blockIdx.x * 256 + threadIdx.x;
    if (i < B_ * M_) {
        int b = i >> 13, m = i & (M_ - 1);
        int pos = atomicAdd(&fill[b * N_ + idx[i]], 1);
        mlist[(size_t)b * M_ + pos] = m;
    }
}

// ---------------- GEMM2: up[b][m][d] = W2 @ relu(bn(h)) + b2 ----------------
__global__ __launch_bounds__(256) void k_gemm2(const u16* __restrict__ W2b,
                                               const u16* __restrict__ hbuf,
                                               const float* __restrict__ b2,
                                               u16* __restrict__ up) {
    __shared__ u16 At[128 * 32];
    __shared__ u16 Bt[128 * 32];
    const int b  = blockIdx.z;
    const int d0 = blockIdx.y * 128;
    const int m0 = blockIdx.x * 128;
    const int tid = threadIdx.x;
    const int w = tid >> 6, l = tid & 63;
    const int lr = l >> 2, lc = (l & 3) * 8;

    const u16* pA[2]; const u16* pB[2];
#pragma unroll
    for (int t = 0; t < 2; ++t) {
        int row = t * 64 + w * 16 + lr;
        pA[t] = W2b + (size_t)(d0 + row) * K2_ + lc;
        int m  = m0 + row;
        pB[t] = hbuf + (size_t)(b * M_ + m) * O1_ + lc;
    }
    const int wr = w >> 1, wc = w & 1;
    f4 acc[4][4];
#pragma unroll
    for (int i = 0; i < 4; ++i)
#pragma unroll
        for (int j = 0; j < 4; ++j) acc[i][j] = {0.f, 0.f, 0.f, 0.f};

    const int aoff = (wr * 64 + (l & 15)) * 32 + (l >> 4) * 8;
    const int boff = (wc * 64 + (l & 15)) * 32 + (l >> 4) * 8;

    for (int kk = 0; kk < 16; ++kk) {
#pragma unroll
        for (int t = 0; t < 2; ++t) {
            gl_lds16(pA[t] + kk * 32, At + (t * 64 + w * 16) * 32);
            gl_lds16(pB[t] + kk * 32, Bt + (t * 64 + w * 16) * 32);
        }
        __syncthreads();
        bf8 aF[4], bF[4];
#pragma unroll
        for (int i = 0; i < 4; ++i) aF[i] = *reinterpret_cast<const bf8*>(&At[aoff + i * 16 * 32]);
#pragma unroll
        for (int j = 0; j < 4; ++j) bF[j] = *reinterpret_cast<const bf8*>(&Bt[boff + j * 16 * 32]);
#pragma unroll
        for (int i = 0; i < 4; ++i)
#pragma unroll
            for (int j = 0; j < 4; ++j)
                acc[i][j] = __builtin_amdgcn_mfma_f32_16x16x32_bf16(aF[i], bF[j], acc[i][j], 0, 0, 0);
        __syncthreads();
    }

    // epilogue: +b2, plain bf16 stores to up[b][m][d]
#pragma unroll
    for (int j = 0; j < 4; ++j) {
        int m = m0 + wc * 64 + j * 16 + (l & 15);
        size_t rowbase = (size_t)(b * M_ + m) * D_;
#pragma unroll
        for (int i = 0; i < 4; ++i) {
            int d = d0 + wr * 64 + i * 16 + (l >> 4) * 4;
            ushort4 pk;
            pk.x = f2bf(acc[i][j].x + b2[d + 0]);
            pk.y = f2bf(acc[i][j].y + b2[d + 1]);
            pk.z = f2bf(acc[i][j].z + b2[d + 2]);
            pk.w = f2bf(acc[i][j].w + b2[d + 3]);
            *reinterpret_cast<ushort4*>(&up[rowbase + d]) = pk;
        }
    }
}

// ---------------- out[b][d][n] = ldesc + mean_{m in list(n)} up[b][m][d] ----------------
__global__ __launch_bounds__(256) void k_reduce_finalize(const float* __restrict__ ldesc,
                                                         const u16* __restrict__ up,
                                                         const int* __restrict__ cnt,
                                                         const int* __restrict__ offs,
                                                         const int* __restrict__ mlist,
                                                         float* __restrict__ out) {
    __shared__ float lds[32][257];
    const int b  = blockIdx.z;
    const int n0 = blockIdx.x * 32;
    const int tx = threadIdx.x, ty = threadIdx.y;   // (32,8)
#pragma unroll
    for (int i = 0; i < 4; ++i) {
        int nl = ty + i * 8;
        int n  = n0 + nl;
        int c   = cnt[b * N_ + n];
        int off = offs[b * N_ + n];
        float inv = 1.0f / (float)max(c, 1);
        float acc[8] = {0.f, 0.f, 0.f, 0.f, 0.f, 0.f, 0.f, 0.f};
        for (int e = 0; e < c; ++e) {
            int m = mlist[(size_t)b * M_ + off + e];
            const ushort4* row = reinterpret_cast<const ushort4*>(up + (size_t)(b * M_ + m) * D_ + tx * 8);
            ushort4 aa = row[0], bb = row[1];
            acc[0] += bf2f(aa.x); acc[1] += bf2f(aa.y); acc[2] += bf2f(aa.z); acc[3] += bf2f(aa.w);
            acc[4] += bf2f(bb.x); acc[5] += bf2f(bb.y); acc[6] += bf2f(bb.z); acc[7] += bf2f(bb.w);
        }
#pragma unroll
        for (int k = 0; k < 8; ++k) lds[nl][tx * 8 + k] = acc[k] * inv;
    }
    __syncthreads();
#pragma unroll
    for (int i = 0; i < 32; ++i) {
        int d = ty + i * 8;
        size_t o2 = (size_t)(b * D_ + d) * N_ + n0 + tx;
        out[o2] = ldesc[o2] + lds[tx][d];
    }
}

__global__ void k_marker(float* out, float v) { out[0] = v; }

extern "C" void kernel_launch(void* const* d_in, const int* in_sizes, int n_in,
                              void* d_out, int out_size, void* d_ws, size_t ws_size,
                              hipStream_t stream) {
    const float* ldesc0 = (const float*)d_in[0];
    const float* ldesc1 = (const float*)d_in[1];
    const float* le0    = (const float*)d_in[2];
    const float* le1    = (const float*)d_in[3];
    const int*   idx0   = (const int*)d_in[4];
    const int*   idx1   = (const int*)d_in[5];
    const float* W1     = (const float*)d_in[6];
    const float* b1     = (const float*)d_in[7];
    const float* g1     = (const float*)d_in[8];
    const float* bt1    = (const float*)d_in[9];
    const float* W2     = (const float*)d_in[10];
    const float* b2     = (const float*)d_in[11];
    float* out = (float*)d_out;

    char* ws = (char*)d_ws;
    const size_t oTld   = 0;                            // bf16 [B][N][D] 33.5MB; aliased by `up` after gemm1
    const size_t oTle   = 33554432;                     // bf16 [B][M][D] 33.5MB; aliased by CSR after gemm1
    const size_t oH     = 67108864;                     // bf16 [B][M][O1] 67MB
    const size_t oW1b   = 134217728;                    // 786,432 B
    const size_t oW2b   = oW1b + 786432;                // 262,144 B
    const size_t oStats = oW2b + 262144;                // 4,096 B
    const size_t oAC    = oStats + 4096;                // 4,096 B
    const size_t NEED   = oAC + 4096;
    if (ws_size < NEED) {
        k_marker<<<1, 1, 0, stream>>>(out, 1000.0f + (float)(ws_size >> 20));
        return;
    }
    u16*   Tld   = (u16*)(ws + oTld);
    u16*   up    = (u16*)(ws + oTld);                   // alias (Tld dead after gemm1)
    u16*   Tle   = (u16*)(ws + oTle);
    int*   cnt   = (int*)(ws + oTle);                   // CSR aliases Tle (dead after gemm1)
    int*   offs  = (int*)(ws + oTle + 262144);
    int*   fill  = (int*)(ws + oTle + 524288);
    int*   mlist = (int*)(ws + oTle + 786432);
    u16*   hbuf  = (u16*)(ws + oH);
    u16*   W1b   = (u16*)(ws + oW1b);
    u16*   W2b   = (u16*)(ws + oW2b);
    float* stats = (float*)(ws + oStats);
    float* ac    = (float*)(ws + oAC);

    k_convert_w<<<2048, 256, 0, stream>>>(W1, W2, W1b, W2b);

    const dim3 tb(32, 8);
    for (int s = 0; s < 2; ++s) {
        const float* ld  = s ? ldesc1 : ldesc0;
        const float* le  = s ? le1 : le0;
        const int*   idx = s ? idx1 : idx0;
        float* outp = out + (size_t)s * B_ * D_ * N_;

        k_transpose_bf16<<<dim3(N_ / 32, D_ / 32, B_), tb, 0, stream>>>(ld, Tld, D_, N_);
        k_transpose_bf16<<<dim3(M_ / 32, D_ / 32, B_), tb, 0, stream>>>(le, Tle, D_, M_);
        k_gemm1<<<dim3(M_ / 128, O1_ / 128, B_), 256, 0, stream>>>(W1b, Tld, Tle, idx, b1, hbuf);
        // BN stats + apply
        hipMemsetAsync(stats, 0, 4096, stream);
        k_stats<<<256, 256, 0, stream>>>(hbuf, stats);
        k_finalize_ac<<<2, 256, 0, stream>>>(stats, g1, bt1, ac);
        k_bnrelu<<<2048, 256, 0, stream>>>(hbuf, ac);
        // CSR of idx (Tle region is dead now)
        hipMemsetAsync(cnt, 0, (size_t)B_ * N_ * 4, stream);
        k_count_int<<<B_ * M_ / 256, 256, 0, stream>>>(idx, cnt);
        k_scan<<<B_, 1024, 0, stream>>>(cnt, offs, fill);
        k_fill<<<B_ * M_ / 256, 256, 0, stream>>>(idx, fill, mlist);
        // GEMM2 -> up (Tld region is dead now), then gather-mean + residual
        k_gemm2<<<dim3(M_ / 128, D_ / 128, B_), 256, 0, stream>>>(W2b, hbuf, b2, up);
        k_reduce_finalize<<<dim3(N_ / 32, 1, B_), tb, 0, stream>>>(ld, up, cnt, offs, mlist, outp);
    }
}

// Round 5
// 488.752 us; speedup vs baseline: 1.8466x; 1.0342x over previous
//
#include <hip/hip_runtime.h>
#include <hip/hip_bf16.h>

#define B_  8
#define D_  256
#define N_  8192
#define M_  8192
#define O1_ 512     // 2D
#define K1_ 768     // 3D
#define K2_ 512     // 2D

typedef unsigned short u16;
typedef __attribute__((ext_vector_type(8))) short bf8;   // 8 bf16 = 4 VGPRs
typedef __attribute__((ext_vector_type(4))) float f4;

static __device__ __forceinline__ float bf2f(u16 u) {
    unsigned v = ((unsigned)u) << 16;
    return __uint_as_float(v);
}
static __device__ __forceinline__ u16 f2bf(float f) {
    __hip_bfloat16 h = __float2bfloat16(f);
    return *reinterpret_cast<u16*>(&h);
}
// async global->LDS, 16B per lane; LDS dest = wave-uniform base + lane*16
static __device__ __forceinline__ void gl_lds16(const u16* g, u16* l) {
    __builtin_amdgcn_global_load_lds((const __attribute__((address_space(1))) void*)g,
                                     (__attribute__((address_space(3))) void*)l, 16, 0, 0);
}

// ---------------- transpose f32 [B][R][C] -> bf16 [B][C][R] ----------------
__global__ __launch_bounds__(256) void k_transpose_bf16(const float* __restrict__ src,
                                                        u16* __restrict__ dst, int R, int C) {
    __shared__ float t[32][33];
    const int b  = blockIdx.z;
    const int c0 = blockIdx.x * 32, r0 = blockIdx.y * 32;
    const int tx = threadIdx.x, ty = threadIdx.y;     // block (32,8)
    const float* s = src + (size_t)b * R * C;
    u16* d = dst + (size_t)b * C * R;
#pragma unroll
    for (int i = 0; i < 4; ++i) {
        int r = r0 + ty + i * 8;
        t[ty + i * 8][tx] = s[(size_t)r * C + (c0 + tx)];
    }
    __syncthreads();
#pragma unroll
    for (int i = 0; i < 4; ++i) {
        int c = c0 + ty + i * 8;
        d[(size_t)c * R + (r0 + tx)] = f2bf(t[tx][ty + i * 8]);
    }
}

// ---------------- weights f32 -> bf16 ----------------
__global__ __launch_bounds__(256) void k_convert_w(const float* __restrict__ W1, const float* __restrict__ W2,
                                                   u16* __restrict__ W1b, u16* __restrict__ W2b) {
    int i = blockIdx.x * 256 + threadIdx.x;
    const int n1 = O1_ * K1_;
    const int n2 = D_ * K2_;
    if (i < n1) W1b[i] = f2bf(W1[i]);
    int j = i - n1;
    if (j >= 0 && j < n2) W2b[j] = f2bf(W2[j]);
}

// ---------------- GEMM1: h[b][m][o] = W1 @ msg + b1; fused per-channel stats ----------------
// msg k-segments: [0,256) Tld[idx[m]], [256,512) Tld[idx[m^1]], [512,768) Tle[m]
__global__ __launch_bounds__(256) void k_gemm1(const u16* __restrict__ W1b,
                                               const u16* __restrict__ Tld,
                                               const u16* __restrict__ Tle,
                                               const int* __restrict__ idx,
                                               const float* __restrict__ b1,
                                               u16* __restrict__ hbuf,
                                               float* __restrict__ stats) {
    __shared__ u16 At[128 * 32];
    __shared__ u16 Bt[128 * 32];
    const int b  = blockIdx.z;
    const int o0 = blockIdx.y * 128;
    const int m0 = blockIdx.x * 128;
    const int tid = threadIdx.x;
    const int w = tid >> 6, l = tid & 63;
    const int lr = l >> 2;          // staging row-in-group 0..15
    const int lc = (l & 3) * 8;     // ushort offset (16B) within 64B row

    const u16* pA[2]; const u16* pB0[2]; const u16* pB1[2]; const u16* pB2[2];
#pragma unroll
    for (int t = 0; t < 2; ++t) {
        int row = t * 64 + w * 16 + lr;                  // 0..127
        pA[t] = W1b + (size_t)(o0 + row) * K1_ + lc;
        int m  = m0 + row;
        int na = idx[b * M_ + m];
        int nb = idx[b * M_ + (m ^ 1)];
        pB0[t] = Tld + (size_t)(b * N_ + na) * D_ + lc;
        pB1[t] = Tld + (size_t)(b * N_ + nb) * D_ + lc;
        pB2[t] = Tle + (size_t)(b * M_ + m) * D_ + lc;
    }

    const int wr = w >> 1, wc = w & 1;
    f4 acc[4][4];
#pragma unroll
    for (int i = 0; i < 4; ++i)
#pragma unroll
        for (int j = 0; j < 4; ++j) acc[i][j] = {0.f, 0.f, 0.f, 0.f};

    const int aoff = (wr * 64 + (l & 15)) * 32 + (l >> 4) * 8;
    const int boff = (wc * 64 + (l & 15)) * 32 + (l >> 4) * 8;

    for (int kk = 0; kk < 24; ++kk) {
        const int seg  = kk >> 3;
        const int coff = (kk & 7) * 32;   // ushorts within source row
#pragma unroll
        for (int t = 0; t < 2; ++t) {
            gl_lds16(pA[t] + kk * 32, At + (t * 64 + w * 16) * 32);
            const u16* src = (seg == 0) ? (pB0[t] + coff)
                           : (seg == 1) ? (pB1[t] + coff)
                                        : (pB2[t] + coff);
            gl_lds16(src, Bt + (t * 64 + w * 16) * 32);
        }
        __syncthreads();
        bf8 aF[4], bF[4];
#pragma unroll
        for (int i = 0; i < 4; ++i) aF[i] = *reinterpret_cast<const bf8*>(&At[aoff + i * 16 * 32]);
#pragma unroll
        for (int j = 0; j < 4; ++j) bF[j] = *reinterpret_cast<const bf8*>(&Bt[boff + j * 16 * 32]);
#pragma unroll
        for (int i = 0; i < 4; ++i)
#pragma unroll
            for (int j = 0; j < 4; ++j)
                acc[i][j] = __builtin_amdgcn_mfma_f32_16x16x32_bf16(aF[i], bF[j], acc[i][j], 0, 0, 0);
        __syncthreads();
    }

    // add b1 in-register (stats must include it)
#pragma unroll
    for (int i = 0; i < 4; ++i) {
        int orow = o0 + wr * 64 + i * 16 + (l >> 4) * 4;
        float b0v = b1[orow + 0], b1v = b1[orow + 1], b2v = b1[orow + 2], b3v = b1[orow + 3];
#pragma unroll
        for (int j = 0; j < 4; ++j) {
            acc[i][j].x += b0v; acc[i][j].y += b1v; acc[i][j].z += b2v; acc[i][j].w += b3v;
        }
    }

    // fused BN stats: per-channel partial sum / sumsq over this block's 128 m-values.
    // After the final k-loop barrier, At is dead -> reuse as f32 scratch [128ch][2wc] x {S,Q}.
    float* redS = (float*)At;          // 128*2 floats = 1KB
    float* redQ = (float*)At + 256;    // next 1KB
#pragma unroll
    for (int i = 0; i < 4; ++i) {
#pragma unroll
        for (int r = 0; r < 4; ++r) {
            float s = acc[i][0][r] + acc[i][1][r] + acc[i][2][r] + acc[i][3][r];
            float q = acc[i][0][r] * acc[i][0][r] + acc[i][1][r] * acc[i][1][r]
                    + acc[i][2][r] * acc[i][2][r] + acc[i][3][r] * acc[i][3][r];
#pragma unroll
            for (int mm = 1; mm < 16; mm <<= 1) {
                s += __shfl_xor(s, mm, 16);
                q += __shfl_xor(q, mm, 16);
            }
            if ((l & 15) == 0) {
                int ch = wr * 64 + i * 16 + (l >> 4) * 4 + r;
                redS[ch * 2 + wc] = s;
                redQ[ch * 2 + wc] = q;
            }
        }
    }
    __syncthreads();
    if (tid < 128) {
        atomicAdd(&stats[o0 + tid],        redS[tid * 2] + redS[tid * 2 + 1]);
        atomicAdd(&stats[O1_ + o0 + tid],  redQ[tid * 2] + redQ[tid * 2 + 1]);
    }

    // store bf16 h (b1 already added)
#pragma unroll
    for (int j = 0; j < 4; ++j) {
        int m = m0 + wc * 64 + j * 16 + (l & 15);
        size_t rowbase = (size_t)(b * M_ + m) * O1_;
#pragma unroll
        for (int i = 0; i < 4; ++i) {
            int orow = o0 + wr * 64 + i * 16 + (l >> 4) * 4;
            ushort4 pk;
            pk.x = f2bf(acc[i][j].x);
            pk.y = f2bf(acc[i][j].y);
            pk.z = f2bf(acc[i][j].z);
            pk.w = f2bf(acc[i][j].w);
            *reinterpret_cast<ushort4*>(&hbuf[rowbase + orow]) = pk;
        }
    }
}

__global__ void k_finalize_ac(const float* __restrict__ stats, const float* __restrict__ g1,
                              const float* __restrict__ bt1, float* __restrict__ ac) {
    int o = blockIdx.x * 256 + threadIdx.x;
    if (o >= O1_) return;
    const float inv = 1.0f / ((float)B_ * (float)M_);
    float mean = stats[o] * inv;
    float var  = stats[O1_ + o] * inv - mean * mean;
    var = fmaxf(var, 0.0f);
    float a = g1[o] * rsqrtf(var + 1e-5f);
    ac[o] = a;
    ac[O1_ + o] = bt1[o] - mean * a;
}

// ---------------- CSR build: count -> scan -> fill ----------------
__global__ void k_count_int(const int* __restrict__ idx, int* __restrict__ cnt) {
    int i = blockIdx.x * 256 + threadIdx.x;
    if (i < B_ * M_) atomicAdd(&cnt[(i >> 13) * N_ + idx[i]], 1);
}

__global__ __launch_bounds__(1024) void k_scan(const int* __restrict__ cnt, int* __restrict__ offs,
                                               int* __restrict__ fill) {
    __shared__ int wsum[1024];
    const int b = blockIdx.x;
    const int t = threadIdx.x;
    const int base = b * N_;
    int v[8]; int s = 0;
#pragma unroll
    for (int k = 0; k < 8; ++k) { v[k] = cnt[base + t * 8 + k]; s += v[k]; }
    wsum[t] = s;
    __syncthreads();
    for (int off = 1; off < 1024; off <<= 1) {
        int add = (t >= off) ? wsum[t - off] : 0;
        __syncthreads();
        wsum[t] += add;
        __syncthreads();
    }
    int run = (t > 0) ? wsum[t - 1] : 0;
#pragma unroll
    for (int k = 0; k < 8; ++k) {
        offs[base + t * 8 + k] = run;
        fill[base + t * 8 + k] = run;
        run += v[k];
    }
}

__global__ void k_fill(const int* __restrict__ idx, int* __restrict__ fill, int* __restrict__ mlist) {
    int i = blockIdx.x * 256 + threadIdx.x;
    if (i < B_ * M_) {
        int b = i >> 13, m = i & (M_ - 1);
        int pos = atomicAdd(&fill[b * N_ + idx[i]], 1);
        mlist[(size_t)b * M_ + pos] = m;
    }
}

// ---------------- GEMM2: up[b][m][d] = W2 @ relu(a*h+c) + b2 (BN+ReLU fused into B-staging) ----------------
__global__ __launch_bounds__(256) void k_gemm2(const u16* __restrict__ W2b,
                                               const u16* __restrict__ hbuf,
                                               const float* __restrict__ ac,
                                               const float* __restrict__ b2,
                                               u16* __restrict__ up) {
    __shared__ u16 At[128 * 32];
    __shared__ u16 Bt[128 * 32];
    __shared__ float acs[1024];    // [0,512) scale a, [512,1024) shift c
    const int b  = blockIdx.z;
    const int d0 = blockIdx.y * 128;
    const int m0 = blockIdx.x * 128;
    const int tid = threadIdx.x;
    const int w = tid >> 6, l = tid & 63;
    const int lr = l >> 2, lc = (l & 3) * 8;

    acs[tid]       = ac[tid];
    acs[tid + 256] = ac[tid + 256];
    acs[tid + 512] = ac[tid + 512];
    acs[tid + 768] = ac[tid + 768];

    const u16* pA[2]; const u16* pB[2];
#pragma unroll
    for (int t = 0; t < 2; ++t) {
        int row = t * 64 + w * 16 + lr;
        pA[t] = W2b + (size_t)(d0 + row) * K2_ + lc;
        int m  = m0 + row;
        pB[t] = hbuf + (size_t)(b * M_ + m) * O1_ + lc;
    }
    const int wr = w >> 1, wc = w & 1;
    f4 acc[4][4];
#pragma unroll
    for (int i = 0; i < 4; ++i)
#pragma unroll
        for (int j = 0; j < 4; ++j) acc[i][j] = {0.f, 0.f, 0.f, 0.f};

    const int aoff = (wr * 64 + (l & 15)) * 32 + (l >> 4) * 8;
    const int boff = (wc * 64 + (l & 15)) * 32 + (l >> 4) * 8;
    const int bdst = (w * 16 + lr) * 32 + lc;   // +t*64*32 per chunk

    __syncthreads();   // acs visible before first transform

    for (int kk = 0; kk < 16; ++kk) {
        const int o = kk * 32 + lc;
        f4 A0 = *reinterpret_cast<const f4*>(&acs[o]);
        f4 A1 = *reinterpret_cast<const f4*>(&acs[o + 4]);
        f4 C0 = *reinterpret_cast<const f4*>(&acs[512 + o]);
        f4 C1 = *reinterpret_cast<const f4*>(&acs[512 + o + 4]);
#pragma unroll
        for (int t = 0; t < 2; ++t) {
            gl_lds16(pA[t] + kk * 32, At + (t * 64 + w * 16) * 32);
            const ushort4* ps = reinterpret_cast<const ushort4*>(pB[t] + kk * 32);
            ushort4 v0 = ps[0], v1 = ps[1];
            union { ushort4 u4[2]; bf8 v8; } pk;
            pk.u4[0].x = f2bf(fmaxf(bf2f(v0.x) * A0.x + C0.x, 0.0f));
            pk.u4[0].y = f2bf(fmaxf(bf2f(v0.y) * A0.y + C0.y, 0.0f));
            pk.u4[0].z = f2bf(fmaxf(bf2f(v0.z) * A0.z + C0.z, 0.0f));
            pk.u4[0].w = f2bf(fmaxf(bf2f(v0.w) * A0.w + C0.w, 0.0f));
            pk.u4[1].x = f2bf(fmaxf(bf2f(v1.x) * A1.x + C1.x, 0.0f));
            pk.u4[1].y = f2bf(fmaxf(bf2f(v1.y) * A1.y + C1.y, 0.0f));
            pk.u4[1].z = f2bf(fmaxf(bf2f(v1.z) * A1.z + C1.z, 0.0f));
            pk.u4[1].w = f2bf(fmaxf(bf2f(v1.w) * A1.w + C1.w, 0.0f));
            *reinterpret_cast<bf8*>(&Bt[t * 64 * 32 + bdst]) = pk.v8;
        }
        __syncthreads();
        bf8 aF[4], bF[4];
#pragma unroll
        for (int i = 0; i < 4; ++i) aF[i] = *reinterpret_cast<const bf8*>(&At[aoff + i * 16 * 32]);
#pragma unroll
        for (int j = 0; j < 4; ++j) bF[j] = *reinterpret_cast<const bf8*>(&Bt[boff + j * 16 * 32]);
#pragma unroll
        for (int i = 0; i < 4; ++i)
#pragma unroll
            for (int j = 0; j < 4; ++j)
                acc[i][j] = __builtin_amdgcn_mfma_f32_16x16x32_bf16(aF[i], bF[j], acc[i][j], 0, 0, 0);
        __syncthreads();
    }

    // epilogue: +b2, plain bf16 stores to up[b][m][d]
#pragma unroll
    for (int j = 0; j < 4; ++j) {
        int m = m0 + wc * 64 + j * 16 + (l & 15);
        size_t rowbase = (size_t)(b * M_ + m) * D_;
#pragma unroll
        for (int i = 0; i < 4; ++i) {
            int d = d0 + wr * 64 + i * 16 + (l >> 4) * 4;
            ushort4 pk;
            pk.x = f2bf(acc[i][j].x + b2[d + 0]);
            pk.y = f2bf(acc[i][j].y + b2[d + 1]);
            pk.z = f2bf(acc[i][j].z + b2[d + 2]);
            pk.w = f2bf(acc[i][j].w + b2[d + 3]);
            *reinterpret_cast<ushort4*>(&up[rowbase + d]) = pk;
        }
    }
}

// ---------------- out[b][d][n] = ldesc + mean_{m in list(n)} up[b][m][d] ----------------
__global__ __launch_bounds__(256) void k_reduce_finalize(const float* __restrict__ ldesc,
                                                         const u16* __restrict__ up,
                                                         const int* __restrict__ cnt,
                                                         const int* __restrict__ offs,
                                                         const int* __restrict__ mlist,
                                                         float* __restrict__ out) {
    __shared__ float lds[32][257];
    const int b  = blockIdx.z;
    const int n0 = blockIdx.x * 32;
    const int tx = threadIdx.x, ty = threadIdx.y;   // (32,8)
#pragma unroll
    for (int i = 0; i < 4; ++i) {
        int nl = ty + i * 8;
        int n  = n0 + nl;
        int c   = cnt[b * N_ + n];
        int off = offs[b * N_ + n];
        float inv = 1.0f / (float)max(c, 1);
        float acc[8] = {0.f, 0.f, 0.f, 0.f, 0.f, 0.f, 0.f, 0.f};
        for (int e = 0; e < c; ++e) {
            int m = mlist[(size_t)b * M_ + off + e];
            const ushort4* row = reinterpret_cast<const ushort4*>(up + (size_t)(b * M_ + m) * D_ + tx * 8);
            ushort4 aa = row[0], bb = row[1];
            acc[0] += bf2f(aa.x); acc[1] += bf2f(aa.y); acc[2] += bf2f(aa.z); acc[3] += bf2f(aa.w);
            acc[4] += bf2f(bb.x); acc[5] += bf2f(bb.y); acc[6] += bf2f(bb.z); acc[7] += bf2f(bb.w);
        }
#pragma unroll
        for (int k = 0; k < 8; ++k) lds[nl][tx * 8 + k] = acc[k] * inv;
    }
    __syncthreads();
#pragma unroll
    for (int i = 0; i < 32; ++i) {
        int d = ty + i * 8;
        size_t o2 = (size_t)(b * D_ + d) * N_ + n0 + tx;
        out[o2] = ldesc[o2] + lds[tx][d];
    }
}

__global__ void k_marker(float* out, float v) { out[0] = v; }

extern "C" void kernel_launch(void* const* d_in, const int* in_sizes, int n_in,
                              void* d_out, int out_size, void* d_ws, size_t ws_size,
                              hipStream_t stream) {
    const float* ldesc0 = (const float*)d_in[0];
    const float* ldesc1 = (const float*)d_in[1];
    const float* le0    = (const float*)d_in[2];
    const float* le1    = (const float*)d_in[3];
    const int*   idx0   = (const int*)d_in[4];
    const int*   idx1   = (const int*)d_in[5];
    const float* W1     = (const float*)d_in[6];
    const float* b1     = (const float*)d_in[7];
    const float* g1     = (const float*)d_in[8];
    const float* bt1    = (const float*)d_in[9];
    const float* W2     = (const float*)d_in[10];
    const float* b2     = (const float*)d_in[11];
    float* out = (float*)d_out;

    char* ws = (char*)d_ws;
    const size_t oTld   = 0;                            // bf16 [B][N][D] 33.5MB; aliased by `up` after gemm1
    const size_t oTle   = 33554432;                     // bf16 [B][M][D] 33.5MB; aliased by CSR after gemm1
    const size_t oH     = 67108864;                     // bf16 [B][M][O1] 67MB
    const size_t oW1b   = 134217728;                    // 786,432 B
    const size_t oW2b   = oW1b + 786432;                // 262,144 B
    const size_t oStats = oW2b + 262144;                // 4,096 B
    const size_t oAC    = oStats + 4096;                // 4,096 B
    const size_t NEED   = oAC + 4096;
    if (ws_size < NEED) {
        k_marker<<<1, 1, 0, stream>>>(out, 1000.0f + (float)(ws_size >> 20));
        return;
    }
    u16*   Tld   = (u16*)(ws + oTld);
    u16*   up    = (u16*)(ws + oTld);                   // alias (Tld dead after gemm1)
    u16*   Tle   = (u16*)(ws + oTle);
    int*   cnt   = (int*)(ws + oTle);                   // CSR aliases Tle (dead after gemm1)
    int*   offs  = (int*)(ws + oTle + 262144);
    int*   fill  = (int*)(ws + oTle + 524288);
    int*   mlist = (int*)(ws + oTle + 786432);
    u16*   hbuf  = (u16*)(ws + oH);
    u16*   W1b   = (u16*)(ws + oW1b);
    u16*   W2b   = (u16*)(ws + oW2b);
    float* stats = (float*)(ws + oStats);
    float* ac    = (float*)(ws + oAC);

    k_convert_w<<<2048, 256, 0, stream>>>(W1, W2, W1b, W2b);

    const dim3 tb(32, 8);
    for (int s = 0; s < 2; ++s) {
        const float* ld  = s ? ldesc1 : ldesc0;
        const float* le  = s ? le1 : le0;
        const int*   idx = s ? idx1 : idx0;
        float* outp = out + (size_t)s * B_ * D_ * N_;

        k_transpose_bf16<<<dim3(N_ / 32, D_ / 32, B_), tb, 0, stream>>>(ld, Tld, D_, N_);
        k_transpose_bf16<<<dim3(M_ / 32, D_ / 32, B_), tb, 0, stream>>>(le, Tle, D_, M_);
        hipMemsetAsync(stats, 0, 4096, stream);
        k_gemm1<<<dim3(M_ / 128, O1_ / 128, B_), 256, 0, stream>>>(W1b, Tld, Tle, idx, b1, hbuf, stats);
        k_finalize_ac<<<2, 256, 0, stream>>>(stats, g1, bt1, ac);
        // CSR of idx (Tle region is dead now)
        hipMemsetAsync(cnt, 0, (size_t)B_ * N_ * 4, stream);
        k_count_int<<<B_ * M_ / 256, 256, 0, stream>>>(idx, cnt);
        k_scan<<<B_, 1024, 0, stream>>>(cnt, offs, fill);
        k_fill<<<B_ * M_ / 256, 256, 0, stream>>>(idx, fill, mlist);
        // GEMM2 (fused BN+ReLU) -> up (Tld region is dead now), then gather-mean + residual
        k_gemm2<<<dim3(M_ / 128, D_ / 128, B_), 256, 0, stream>>>(W2b, hbuf, ac, b2, up);
        k_reduce_finalize<<<dim3(N_ / 32, 1, B_), tb, 0, stream>>>(ld, up, cnt, offs, mlist, outp);
    }
}

// Round 6
// 476.342 us; speedup vs baseline: 1.8947x; 1.0261x over previous
//
#include <hip/hip_runtime.h>
#include <hip/hip_bf16.h>

#define B_  8
#define D_  256
#define N_  8192
#define M_  8192
#define O1_ 512     // 2D
#define K1_ 768     // 3D
#define K2_ 512     // 2D

typedef unsigned short u16;
typedef __attribute__((ext_vector_type(8))) short bf8;   // 8 bf16 = 4 VGPRs
typedef __attribute__((ext_vector_type(4))) float f4;

static __device__ __forceinline__ float bf2f(u16 u) {
    unsigned v = ((unsigned)u) << 16;
    return __uint_as_float(v);
}
static __device__ __forceinline__ u16 f2bf(float f) {
    __hip_bfloat16 h = __float2bfloat16(f);
    return *reinterpret_cast<u16*>(&h);
}
// async global->LDS, 16B per lane; LDS dest = wave-uniform base + lane*16
static __device__ __forceinline__ void gl_lds16(const u16* g, u16* l) {
    __builtin_amdgcn_global_load_lds((const __attribute__((address_space(1))) void*)g,
                                     (__attribute__((address_space(3))) void*)l, 16, 0, 0);
}

// ---------------- transpose f32 [B][R][C] -> bf16 [B][C][R] ----------------
__global__ __launch_bounds__(256) void k_transpose_bf16(const float* __restrict__ src,
                                                        u16* __restrict__ dst, int R, int C) {
    __shared__ float t[32][33];
    const int b  = blockIdx.z;
    const int c0 = blockIdx.x * 32, r0 = blockIdx.y * 32;
    const int tx = threadIdx.x, ty = threadIdx.y;     // block (32,8)
    const float* s = src + (size_t)b * R * C;
    u16* d = dst + (size_t)b * C * R;
#pragma unroll
    for (int i = 0; i < 4; ++i) {
        int r = r0 + ty + i * 8;
        t[ty + i * 8][tx] = s[(size_t)r * C + (c0 + tx)];
    }
    __syncthreads();
#pragma unroll
    for (int i = 0; i < 4; ++i) {
        int c = c0 + ty + i * 8;
        d[(size_t)c * R + (r0 + tx)] = f2bf(t[tx][ty + i * 8]);
    }
}

// ---------------- weights f32 -> bf16 ----------------
__global__ __launch_bounds__(256) void k_convert_w(const float* __restrict__ W1, const float* __restrict__ W2,
                                                   u16* __restrict__ W1b, u16* __restrict__ W2b) {
    int i = blockIdx.x * 256 + threadIdx.x;
    const int n1 = O1_ * K1_;
    const int n2 = D_ * K2_;
    if (i < n1) W1b[i] = f2bf(W1[i]);
    int j = i - n1;
    if (j >= 0 && j < n2) W2b[j] = f2bf(W2[j]);
}

// ---------------- GEMM1: h'[b][m][o] = W1 @ msg  (b1 omitted: cancels in BN) ----------------
// msg k-segments: [0,256) Tld[idx[m]], [256,512) Tld[idx[m^1]], [512,768) Tle[m]
__global__ __launch_bounds__(256) void k_gemm1(const u16* __restrict__ W1b,
                                               const u16* __restrict__ Tld,
                                               const u16* __restrict__ Tle,
                                               const int* __restrict__ idx,
                                               u16* __restrict__ hbuf) {
    __shared__ u16 At[128 * 32];
    __shared__ u16 Bt[128 * 32];
    const int b  = blockIdx.z;
    const int o0 = blockIdx.y * 128;
    const int m0 = blockIdx.x * 128;
    const int tid = threadIdx.x;
    const int w = tid >> 6, l = tid & 63;
    const int lr = l >> 2;          // staging row-in-group 0..15
    const int lc = (l & 3) * 8;     // ushort offset (16B) within 64B row

    const u16* pA[2]; const u16* pB0[2]; const u16* pB1[2]; const u16* pB2[2];
#pragma unroll
    for (int t = 0; t < 2; ++t) {
        int row = t * 64 + w * 16 + lr;                  // 0..127
        pA[t] = W1b + (size_t)(o0 + row) * K1_ + lc;
        int m  = m0 + row;
        int na = idx[b * M_ + m];
        int nb = idx[b * M_ + (m ^ 1)];
        pB0[t] = Tld + (size_t)(b * N_ + na) * D_ + lc;
        pB1[t] = Tld + (size_t)(b * N_ + nb) * D_ + lc;
        pB2[t] = Tle + (size_t)(b * M_ + m) * D_ + lc;
    }

    const int wr = w >> 1, wc = w & 1;
    f4 acc[4][4];
#pragma unroll
    for (int i = 0; i < 4; ++i)
#pragma unroll
        for (int j = 0; j < 4; ++j) acc[i][j] = {0.f, 0.f, 0.f, 0.f};

    const int aoff = (wr * 64 + (l & 15)) * 32 + (l >> 4) * 8;
    const int boff = (wc * 64 + (l & 15)) * 32 + (l >> 4) * 8;

    for (int kk = 0; kk < 24; ++kk) {
        const int seg  = kk >> 3;
        const int coff = (kk & 7) * 32;   // ushorts within source row
#pragma unroll
        for (int t = 0; t < 2; ++t) {
            gl_lds16(pA[t] + kk * 32, At + (t * 64 + w * 16) * 32);
            const u16* src = (seg == 0) ? (pB0[t] + coff)
                           : (seg == 1) ? (pB1[t] + coff)
                                        : (pB2[t] + coff);
            gl_lds16(src, Bt + (t * 64 + w * 16) * 32);
        }
        __syncthreads();
        bf8 aF[4], bF[4];
#pragma unroll
        for (int i = 0; i < 4; ++i) aF[i] = *reinterpret_cast<const bf8*>(&At[aoff + i * 16 * 32]);
#pragma unroll
        for (int j = 0; j < 4; ++j) bF[j] = *reinterpret_cast<const bf8*>(&Bt[boff + j * 16 * 32]);
#pragma unroll
        for (int i = 0; i < 4; ++i)
#pragma unroll
            for (int j = 0; j < 4; ++j)
                acc[i][j] = __builtin_amdgcn_mfma_f32_16x16x32_bf16(aF[i], bF[j], acc[i][j], 0, 0, 0);
        __syncthreads();
    }

    // epilogue: store bf16 h' to hbuf[b][m][o] (o fast)
#pragma unroll
    for (int j = 0; j < 4; ++j) {
        int m = m0 + wc * 64 + j * 16 + (l & 15);
        size_t rowbase = (size_t)(b * M_ + m) * O1_;
#pragma unroll
        for (int i = 0; i < 4; ++i) {
            int orow = o0 + wr * 64 + i * 16 + (l >> 4) * 4;
            ushort4 pk;
            pk.x = f2bf(acc[i][j].x);
            pk.y = f2bf(acc[i][j].y);
            pk.z = f2bf(acc[i][j].z);
            pk.w = f2bf(acc[i][j].w);
            *reinterpret_cast<ushort4*>(&hbuf[rowbase + orow]) = pk;
        }
    }
}

// ---------------- per-channel sum / sumsq over h' ----------------
__global__ __launch_bounds__(256) void k_stats(const u16* __restrict__ hbuf, float* __restrict__ stats) {
    const int t = threadIdx.x;
    const size_t row0 = (size_t)blockIdx.x * 256;
    float s0 = 0.f, q0 = 0.f, s1 = 0.f, q1 = 0.f;
    for (int r = 0; r < 256; ++r) {
        const u16* p = hbuf + (row0 + r) * O1_;
        float v0 = bf2f(p[t]);
        float v1 = bf2f(p[t + 256]);
        s0 += v0; q0 += v0 * v0;
        s1 += v1; q1 += v1 * v1;
    }
    atomicAdd(&stats[t], s0);
    atomicAdd(&stats[O1_ + t], q0);
    atomicAdd(&stats[t + 256], s1);
    atomicAdd(&stats[O1_ + t + 256], q1);
}

__global__ void k_finalize_ac(const float* __restrict__ stats, const float* __restrict__ g1,
                              const float* __restrict__ bt1, float* __restrict__ ac) {
    int o = blockIdx.x * 256 + threadIdx.x;
    if (o >= O1_) return;
    const float inv = 1.0f / ((float)B_ * (float)M_);
    float mean = stats[o] * inv;
    float var  = stats[O1_ + o] * inv - mean * mean;
    var = fmaxf(var, 0.0f);
    float a = g1[o] * rsqrtf(var + 1e-5f);
    ac[o] = a;
    ac[O1_ + o] = bt1[o] - mean * a;   // b1 cancels: shift = bt1 - a*mean(h')
}

// ---------------- CSR build: count -> scan -> fill ----------------
__global__ void k_count_int(const int* __restrict__ idx, int* __restrict__ cnt) {
    int i = blockIdx.x * 256 + threadIdx.x;
    if (i < B_ * M_) atomicAdd(&cnt[(i >> 13) * N_ + idx[i]], 1);
}

__global__ __launch_bounds__(1024) void k_scan(const int* __restrict__ cnt, int* __restrict__ offs,
                                               int* __restrict__ fill) {
    __shared__ int wsum[1024];
    const int b = blockIdx.x;
    const int t = threadIdx.x;
    const int base = b * N_;
    int v[8]; int s = 0;
#pragma unroll
    for (int k = 0; k < 8; ++k) { v[k] = cnt[base + t * 8 + k]; s += v[k]; }
    wsum[t] = s;
    __syncthreads();
    for (int off = 1; off < 1024; off <<= 1) {
        int add = (t >= off) ? wsum[t - off] : 0;
        __syncthreads();
        wsum[t] += add;
        __syncthreads();
    }
    int run = (t > 0) ? wsum[t - 1] : 0;
#pragma unroll
    for (int k = 0; k < 8; ++k) {
        offs[base + t * 8 + k] = run;
        fill[base + t * 8 + k] = run;
        run += v[k];
    }
}

__global__ void k_fill(const int* __restrict__ idx, int* __restrict__ fill, int* __restrict__ mlist) {
    int i = blockIdx.x * 256 + threadIdx.x;
    if (i < B_ * M_) {
        int b = i >> 13, m = i & (M_ - 1);
        int pos = atomicAdd(&fill[b * N_ + idx[i]], 1);
        mlist[(size_t)b * M_ + pos] = m;
    }
}

// ---------------- GEMM2: up[b][m][d] = W2 @ relu(a*h'+c) + b2 (BN+ReLU fused into B-staging) ----------------
__global__ __launch_bounds__(256) void k_gemm2(const u16* __restrict__ W2b,
                                               const u16* __restrict__ hbuf,
                                               const float* __restrict__ ac,
                                               const float* __restrict__ b2,
                                               u16* __restrict__ up) {
    __shared__ u16 At[128 * 32];
    __shared__ u16 Bt[128 * 32];
    __shared__ float acs[1024];    // [0,512) scale a, [512,1024) shift c
    const int b  = blockIdx.z;
    const int d0 = blockIdx.y * 128;
    const int m0 = blockIdx.x * 128;
    const int tid = threadIdx.x;
    const int w = tid >> 6, l = tid & 63;
    const int lr = l >> 2, lc = (l & 3) * 8;

    acs[tid]       = ac[tid];
    acs[tid + 256] = ac[tid + 256];
    acs[tid + 512] = ac[tid + 512];
    acs[tid + 768] = ac[tid + 768];

    const u16* pA[2]; const u16* pB[2];
#pragma unroll
    for (int t = 0; t < 2; ++t) {
        int row = t * 64 + w * 16 + lr;
        pA[t] = W2b + (size_t)(d0 + row) * K2_ + lc;
        int m  = m0 + row;
        pB[t] = hbuf + (size_t)(b * M_ + m) * O1_ + lc;
    }
    const int wr = w >> 1, wc = w & 1;
    f4 acc[4][4];
#pragma unroll
    for (int i = 0; i < 4; ++i)
#pragma unroll
        for (int j = 0; j < 4; ++j) acc[i][j] = {0.f, 0.f, 0.f, 0.f};

    const int aoff = (wr * 64 + (l & 15)) * 32 + (l >> 4) * 8;
    const int boff = (wc * 64 + (l & 15)) * 32 + (l >> 4) * 8;
    const int bdst = (w * 16 + lr) * 32 + lc;   // +t*64*32 per chunk

    __syncthreads();   // acs visible before first transform

    for (int kk = 0; kk < 16; ++kk) {
        const int o = kk * 32 + lc;
        f4 A0 = *reinterpret_cast<const f4*>(&acs[o]);
        f4 A1 = *reinterpret_cast<const f4*>(&acs[o + 4]);
        f4 C0 = *reinterpret_cast<const f4*>(&acs[512 + o]);
        f4 C1 = *reinterpret_cast<const f4*>(&acs[512 + o + 4]);
#pragma unroll
        for (int t = 0; t < 2; ++t) {
            gl_lds16(pA[t] + kk * 32, At + (t * 64 + w * 16) * 32);
            const ushort4* ps = reinterpret_cast<const ushort4*>(pB[t] + kk * 32);
            ushort4 v0 = ps[0], v1 = ps[1];
            union { ushort4 u4[2]; bf8 v8; } pk;
            pk.u4[0].x = f2bf(fmaxf(bf2f(v0.x) * A0.x + C0.x, 0.0f));
            pk.u4[0].y = f2bf(fmaxf(bf2f(v0.y) * A0.y + C0.y, 0.0f));
            pk.u4[0].z = f2bf(fmaxf(bf2f(v0.z) * A0.z + C0.z, 0.0f));
            pk.u4[0].w = f2bf(fmaxf(bf2f(v0.w) * A0.w + C0.w, 0.0f));
            pk.u4[1].x = f2bf(fmaxf(bf2f(v1.x) * A1.x + C1.x, 0.0f));
            pk.u4[1].y = f2bf(fmaxf(bf2f(v1.y) * A1.y + C1.y, 0.0f));
            pk.u4[1].z = f2bf(fmaxf(bf2f(v1.z) * A1.z + C1.z, 0.0f));
            pk.u4[1].w = f2bf(fmaxf(bf2f(v1.w) * A1.w + C1.w, 0.0f));
            *reinterpret_cast<bf8*>(&Bt[t * 64 * 32 + bdst]) = pk.v8;
        }
        __syncthreads();
        bf8 aF[4], bF[4];
#pragma unroll
        for (int i = 0; i < 4; ++i) aF[i] = *reinterpret_cast<const bf8*>(&At[aoff + i * 16 * 32]);
#pragma unroll
        for (int j = 0; j < 4; ++j) bF[j] = *reinterpret_cast<const bf8*>(&Bt[boff + j * 16 * 32]);
#pragma unroll
        for (int i = 0; i < 4; ++i)
#pragma unroll
            for (int j = 0; j < 4; ++j)
                acc[i][j] = __builtin_amdgcn_mfma_f32_16x16x32_bf16(aF[i], bF[j], acc[i][j], 0, 0, 0);
        __syncthreads();
    }

    // epilogue: +b2, plain bf16 stores to up[b][m][d]
#pragma unroll
    for (int j = 0; j < 4; ++j) {
        int m = m0 + wc * 64 + j * 16 + (l & 15);
        size_t rowbase = (size_t)(b * M_ + m) * D_;
#pragma unroll
        for (int i = 0; i < 4; ++i) {
            int d = d0 + wr * 64 + i * 16 + (l >> 4) * 4;
            ushort4 pk;
            pk.x = f2bf(acc[i][j].x + b2[d + 0]);
            pk.y = f2bf(acc[i][j].y + b2[d + 1]);
            pk.z = f2bf(acc[i][j].z + b2[d + 2]);
            pk.w = f2bf(acc[i][j].w + b2[d + 3]);
            *reinterpret_cast<ushort4*>(&up[rowbase + d]) = pk;
        }
    }
}

// ---------------- out[b][d][n] = ldesc + mean_{m in list(n)} up[b][m][d] ----------------
__global__ __launch_bounds__(256) void k_reduce_finalize(const float* __restrict__ ldesc,
                                                         const u16* __restrict__ up,
                                                         const int* __restrict__ cnt,
                                                         const int* __restrict__ offs,
                                                         const int* __restrict__ mlist,
                                                         float* __restrict__ out) {
    __shared__ float lds[32][257];
    const int b  = blockIdx.z;
    const int n0 = blockIdx.x * 32;
    const int tx = threadIdx.x, ty = threadIdx.y;   // (32,8)
#pragma unroll
    for (int i = 0; i < 4; ++i) {
        int nl = ty + i * 8;
        int n  = n0 + nl;
        int c   = cnt[b * N_ + n];
        int off = offs[b * N_ + n];
        float inv = 1.0f / (float)max(c, 1);
        float acc[8] = {0.f, 0.f, 0.f, 0.f, 0.f, 0.f, 0.f, 0.f};
        for (int e = 0; e < c; ++e) {
            int m = mlist[(size_t)b * M_ + off + e];
            const ushort4* row = reinterpret_cast<const ushort4*>(up + (size_t)(b * M_ + m) * D_ + tx * 8);
            ushort4 aa = row[0], bb = row[1];
            acc[0] += bf2f(aa.x); acc[1] += bf2f(aa.y); acc[2] += bf2f(aa.z); acc[3] += bf2f(aa.w);
            acc[4] += bf2f(bb.x); acc[5] += bf2f(bb.y); acc[6] += bf2f(bb.z); acc[7] += bf2f(bb.w);
        }
#pragma unroll
        for (int k = 0; k < 8; ++k) lds[nl][tx * 8 + k] = acc[k] * inv;
    }
    __syncthreads();
#pragma unroll
    for (int i = 0; i < 32; ++i) {
        int d = ty + i * 8;
        size_t o2 = (size_t)(b * D_ + d) * N_ + n0 + tx;
        out[o2] = ldesc[o2] + lds[tx][d];
    }
}

__global__ void k_marker(float* out, float v) { out[0] = v; }

extern "C" void kernel_launch(void* const* d_in, const int* in_sizes, int n_in,
                              void* d_out, int out_size, void* d_ws, size_t ws_size,
                              hipStream_t stream) {
    const float* ldesc0 = (const float*)d_in[0];
    const float* ldesc1 = (const float*)d_in[1];
    const float* le0    = (const float*)d_in[2];
    const float* le1    = (const float*)d_in[3];
    const int*   idx0   = (const int*)d_in[4];
    const int*   idx1   = (const int*)d_in[5];
    const float* W1     = (const float*)d_in[6];
    const float* g1     = (const float*)d_in[8];
    const float* bt1    = (const float*)d_in[9];
    const float* W2     = (const float*)d_in[10];
    const float* b2     = (const float*)d_in[11];
    float* out = (float*)d_out;

    char* ws = (char*)d_ws;
    const size_t oTld   = 0;                            // bf16 [B][N][D] 33.5MB; aliased by `up` after gemm1
    const size_t oTle   = 33554432;                     // bf16 [B][M][D] 33.5MB; aliased by CSR after gemm1
    const size_t oH     = 67108864;                     // bf16 [B][M][O1] 67MB
    const size_t oW1b   = 134217728;                    // 786,432 B
    const size_t oW2b   = oW1b + 786432;                // 262,144 B
    const size_t oStats = oW2b + 262144;                // 4,096 B
    const size_t oAC    = oStats + 4096;                // 4,096 B
    const size_t NEED   = oAC + 4096;
    if (ws_size < NEED) {
        k_marker<<<1, 1, 0, stream>>>(out, 1000.0f + (float)(ws_size >> 20));
        return;
    }
    u16*   Tld   = (u16*)(ws + oTld);
    u16*   up    = (u16*)(ws + oTld);                   // alias (Tld dead after gemm1)
    u16*   Tle   = (u16*)(ws + oTle);
    int*   cnt   = (int*)(ws + oTle);                   // CSR aliases Tle (dead after gemm1)
    int*   offs  = (int*)(ws + oTle + 262144);
    int*   fill  = (int*)(ws + oTle + 524288);
    int*   mlist = (int*)(ws + oTle + 786432);
    u16*   hbuf  = (u16*)(ws + oH);
    u16*   W1b   = (u16*)(ws + oW1b);
    u16*   W2b   = (u16*)(ws + oW2b);
    float* stats = (float*)(ws + oStats);
    float* ac    = (float*)(ws + oAC);

    k_convert_w<<<2048, 256, 0, stream>>>(W1, W2, W1b, W2b);

    const dim3 tb(32, 8);
    for (int s = 0; s < 2; ++s) {
        const float* ld  = s ? ldesc1 : ldesc0;
        const float* le  = s ? le1 : le0;
        const int*   idx = s ? idx1 : idx0;
        float* outp = out + (size_t)s * B_ * D_ * N_;

        k_transpose_bf16<<<dim3(N_ / 32, D_ / 32, B_), tb, 0, stream>>>(ld, Tld, D_, N_);
        k_transpose_bf16<<<dim3(M_ / 32, D_ / 32, B_), tb, 0, stream>>>(le, Tle, D_, M_);
        k_gemm1<<<dim3(M_ / 128, O1_ / 128, B_), 256, 0, stream>>>(W1b, Tld, Tle, idx, hbuf);
        // BN stats (streaming) + coefficients
        hipMemsetAsync(stats, 0, 4096, stream);
        k_stats<<<256, 256, 0, stream>>>(hbuf, stats);
        k_finalize_ac<<<2, 256, 0, stream>>>(stats, g1, bt1, ac);
        // CSR of idx (Tle region is dead now)
        hipMemsetAsync(cnt, 0, (size_t)B_ * N_ * 4, stream);
        k_count_int<<<B_ * M_ / 256, 256, 0, stream>>>(idx, cnt);
        k_scan<<<B_, 1024, 0, stream>>>(cnt, offs, fill);
        k_fill<<<B_ * M_ / 256, 256, 0, stream>>>(idx, fill, mlist);
        // GEMM2 (fused BN+ReLU) -> up (Tld region is dead now), then gather-mean + residual
        k_gemm2<<<dim3(M_ / 128, D_ / 128, B_), 256, 0, stream>>>(W2b, hbuf, ac, b2, up);
        k_reduce_finalize<<<dim3(N_ / 32, 1, B_), tb, 0, stream>>>(ld, up, cnt, offs, mlist, outp);
    }
}